// Round 5
// baseline (992.013 us; speedup 1.0000x reference)
//
#include <hip/hip_runtime.h>

#define IMG   256
#define NPIX  65536          // 256*256
#define PH    63             // patches per side
#define NNODE 3969           // PH*PH
#define SN    4000           // padded node stride (mult of 32, 16B-aligned rows)
#define HID   64
#define GH    128
#define BATCH 4

typedef __attribute__((ext_vector_type(8))) short short8;
typedef __attribute__((ext_vector_type(4))) float float4v;
typedef unsigned short ushort_t;

__device__ inline ushort_t f2bf(float f) {
    union { float f; unsigned u; } v; v.f = f;
    unsigned r = v.u + 0x7FFF + ((v.u >> 16) & 1);   // RNE
    return (ushort_t)(r >> 16);
}

// ---------------------------------------------------------------------------
// sup1T[b][g][n] = sum_pix patch[n][pix] * w3[pix][g]   (bf16 out, n-pad zeroed)
// ---------------------------------------------------------------------------
__global__ __launch_bounds__(256) void k_sup1(const float* __restrict__ in,
                                              const float* __restrict__ w3,
                                              ushort_t* __restrict__ sup1T) {
    int b = blockIdx.z;
    int g = blockIdx.y * 8 + (threadIdx.x >> 5);
    int n = blockIdx.x * 32 + (threadIdx.x & 31);
    ushort_t* dst = sup1T + (size_t)b * GH * SN + (size_t)g * SN + n;
    if (n >= NNODE) { *dst = 0; return; }
    int py = n / PH, px = n - py * PH;
    const float* base = in + (size_t)b * NPIX + (py * 4) * IMG + px * 4;
    float acc = 0.f;
#pragma unroll
    for (int i = 0; i < 8; ++i)
#pragma unroll
        for (int j = 0; j < 8; ++j)
            acc += base[i * IMG + j] * w3[(i * 8 + j) * GH + g];
    *dst = f2bf(acc);
}

// ---------------------------------------------------------------------------
// FUSED cvt+GEMM: C[g][n] += sum_k supT[g][k] * bf16(adj[n][k])
// No adjb intermediate: B-operand converted inline from fp32 adj with
// COALESCED staging (lane -> row=t>>5, col=t&31: 32 lanes read 128
// contiguous bytes; 16 passes cover 128 rows x 32 cols; ds_write_b16 into
// the MFMA-ready Bls layout). K split 8 ways (512-col disjoint chunks,
// last = 385 cols zero-guarded) -> 1024 blocks = 4 blocks/CU for latency
// hiding. C accumulated via atomics (memset upstream).
// ---------------------------------------------------------------------------
template <int G>
__global__ __launch_bounds__(256) void k_gemm_cvt(const float* __restrict__ adj,
                                                  const ushort_t* __restrict__ supT,
                                                  float* __restrict__ C) {
    constexpr int FN = (G == 128) ? 4 : 2;
    const int b = blockIdx.z, ks = blockIdx.y;
    const int node0 = blockIdx.x * 128;
    const int t = threadIdx.x;
    const int lane = t & 63, w = t >> 6;
    const int l15 = lane & 15, q = lane >> 4;
    const int wm0 = (G == 128) ? (w & 1) * 64 : 0;
    const int wn0 = (G == 128) ? (w >> 1) * 64 : w * 32;

    __shared__ ushort_t Als[G][72];
    __shared__ ushort_t Bls[128][72];

    const int k0c = ks * 512;
    const int kend = (k0c + 512 < NNODE) ? (k0c + 512) : NNODE;
    const int kiters = (kend - k0c + 31) >> 5;       // 16, or 13 for ks=7
    const int npairs = (kiters + 1) >> 1;            // 8, or 7

    const ushort_t* Ab = supT + (size_t)b * G * SN;
    const float*    Aj = adj  + (size_t)b * NNODE * NNODE;
    float* Cb = C + (size_t)b * G * SN;

    // coalesced cvt-staging coords
    const int brow = t >> 5;                         // 0..7
    const int bcol = t & 31;                         // 0..31

    float4v acc[4][FN];
#pragma unroll
    for (int i = 0; i < 4; ++i)
#pragma unroll
        for (int j = 0; j < FN; ++j)
#pragma unroll
            for (int r = 0; r < 4; ++r) acc[i][j][r] = 0.f;

    for (int kp = 0; kp < npairs; ++kp) {
        const int kb0 = k0c + kp * 64;
        const bool has2 = (kp * 2 + 1 < kiters);     // wave-uniform
        // ---- A staging (bf16, vector) ----
#pragma unroll
        for (int i = 0; i < G / 64; ++i) {
            int idx = t + i * 256;
            int r = idx >> 2, s = idx & 3;
            *(uint4*)&Als[r][s * 8] =
                *(const uint4*)&Ab[(size_t)r * SN + kb0 + s * 8];
        }
        if (has2) {
#pragma unroll
            for (int i = 0; i < G / 64; ++i) {
                int idx = t + i * 256;
                int r = idx >> 2, s = idx & 3;
                *(uint4*)&Als[r][32 + s * 8] =
                    *(const uint4*)&Ab[(size_t)r * SN + kb0 + 32 + s * 8];
            }
        }
        // ---- B staging: coalesced fp32 load + cvt + b16 LDS write ----
        {
            const bool cok0 = (kb0 + bcol) < NNODE;           // const across i
            const bool cok1 = (kb0 + 32 + bcol) < NNODE;
#pragma unroll
            for (int i = 0; i < 16; ++i) {
                int row = brow + i * 8;
                int grow = node0 + row;
                bool rok = grow < NNODE;
                const float* src = Aj + (size_t)grow * NNODE;
                float v0 = (rok && cok0) ? src[kb0 + bcol] : 0.f;
                Bls[row][bcol] = f2bf(v0);
                if (has2) {
                    float v1 = (rok && cok1) ? src[kb0 + 32 + bcol] : 0.f;
                    Bls[row][32 + bcol] = f2bf(v1);
                }
            }
        }
        __syncthreads();
        {
            short8 af[4], bf[FN];
#pragma unroll
            for (int i = 0; i < 4; ++i)
                af[i] = *(const short8*)&Als[wm0 + i * 16 + l15][q * 8];
#pragma unroll
            for (int j = 0; j < FN; ++j)
                bf[j] = *(const short8*)&Bls[wn0 + j * 16 + l15][q * 8];
#pragma unroll
            for (int i = 0; i < 4; ++i)
#pragma unroll
                for (int j = 0; j < FN; ++j)
                    acc[i][j] = __builtin_amdgcn_mfma_f32_16x16x32_bf16(
                        af[i], bf[j], acc[i][j], 0, 0, 0);
        }
        if (has2) {
            short8 af[4], bf[FN];
#pragma unroll
            for (int i = 0; i < 4; ++i)
                af[i] = *(const short8*)&Als[wm0 + i * 16 + l15][32 + q * 8];
#pragma unroll
            for (int j = 0; j < FN; ++j)
                bf[j] = *(const short8*)&Bls[wn0 + j * 16 + l15][32 + q * 8];
#pragma unroll
            for (int i = 0; i < 4; ++i)
#pragma unroll
                for (int j = 0; j < FN; ++j)
                    acc[i][j] = __builtin_amdgcn_mfma_f32_16x16x32_bf16(
                        af[i], bf[j], acc[i][j], 0, 0, 0);
        }
        __syncthreads();
    }
#pragma unroll
    for (int i = 0; i < 4; ++i) {
        int gg = wm0 + i * 16 + q * 4;
#pragma unroll
        for (int j = 0; j < FN; ++j) {
            int nn = node0 + wn0 + j * 16 + l15;
            if (nn < NNODE) {
#pragma unroll
                for (int r = 0; r < 4; ++r)
                    unsafeAtomicAdd(&Cb[(size_t)(gg + r) * SN + nn], acc[i][j][r]);
            }
        }
    }
}

// ---------------------------------------------------------------------------
// sup2T[b][g][n] = sum_k relu(g1T[k][n] + gb3[k]) * w4[k][g]  (bf16, pad zeroed)
// ---------------------------------------------------------------------------
__global__ __launch_bounds__(256) void k_sup2(const float* __restrict__ g1T,
                                              const float* __restrict__ gb3,
                                              const float* __restrict__ w4,
                                              ushort_t* __restrict__ sup2T) {
    int b = blockIdx.z;
    int g = blockIdx.y * 8 + (threadIdx.x >> 5);
    int n = blockIdx.x * 32 + (threadIdx.x & 31);
    const float* gb = g1T + (size_t)b * GH * SN + n;
    float acc = 0.f;
#pragma unroll 8
    for (int k = 0; k < GH; ++k) {
        float v = fmaxf(gb[(size_t)k * SN] + gb3[k], 0.f);
        acc += v * w4[k * 64 + g];
    }
    sup2T[(size_t)b * 64 * SN + (size_t)g * SN + n] = (n < NNODE) ? f2bf(acc) : 0;
}

// ---------------------------------------------------------------------------
// prepack conv2 weights: cw2 [oc][ic][3][3] fp32 -> W2p [tap][oc][ic] bf16
// ---------------------------------------------------------------------------
__global__ __launch_bounds__(256) void k_prepack(const float* __restrict__ w,
                                                 ushort_t* __restrict__ W2p) {
    int idx = blockIdx.x * 256 + threadIdx.x;   // 9*64*64 = 36864
    if (idx >= 36864) return;
    int tap = idx >> 12, rem = idx & 4095;
    int oc = rem >> 6, ic = rem & 63;
    W2p[idx] = f2bf(w[(oc * 64 + ic) * 9 + tap]);
}

// ---------------------------------------------------------------------------
// conv2f: FUSED conv1 -> conv2(MFMA) -> conv3 channel-contraction.
// ---------------------------------------------------------------------------
__global__ __launch_bounds__(256) void k_conv2f(const float* __restrict__ in,
                                                const float* __restrict__ w1,
                                                const float* __restrict__ b1,
                                                const ushort_t* __restrict__ W2p,
                                                const float* __restrict__ b2,
                                                const float* __restrict__ w3c,
                                                float* __restrict__ U) {
    __shared__ ushort_t Xs[340 * 72];           // 48,960 B
    __shared__ float pre[1088];                 // 4,352 B (overlaid)
    const int b = blockIdx.z;
    const float* inb = in + (size_t)b * NPIX;
    float* Uball = U + (size_t)b * 9 * NPIX;
    const int t = threadIdx.x;
    const int lane = t & 63, w = t >> 6;
    const int l15 = lane & 15, q = lane >> 4;
    const int x0 = blockIdx.x * 32, y0 = blockIdx.y * 8;

    float* sI  = pre;                           // [12][36] input halo^2
    float* ws1 = pre + 432;                     // [576] conv1 weights
    float* bs1 = pre + 1008;                    // [64]  conv1 bias

    for (int idx = t; idx < 432; idx += 256) {
        int yy = idx / 36, xx = idx - yy * 36;
        int gy = y0 + yy - 2, gx = x0 + xx - 2;
        sI[idx] = (gy >= 0 && gy < IMG && gx >= 0 && gx < IMG) ? inb[gy * IMG + gx] : 0.f;
    }
    for (int idx = t; idx < 576; idx += 256) ws1[idx] = w1[idx];
    if (t < 64) bs1[t] = b1[t];
    __syncthreads();

    // conv1 -> Xs: 340 halo px x 64 ch (8 ch per (px,s) work item)
    for (int idx = t; idx < 2720; idx += 256) {
        int hp = idx >> 3, s = idx & 7;
        int hy = hp / 34, hx = hp - hy * 34;
        int gy = y0 + hy - 1, gx = x0 + hx - 1;
        unsigned pk[4] = {0u, 0u, 0u, 0u};
        if (gy >= 0 && gy < IMG && gx >= 0 && gx < IMG) {
            float r[9];
#pragma unroll
            for (int dy = 0; dy < 3; ++dy)
#pragma unroll
                for (int dx = 0; dx < 3; ++dx)
                    r[dy * 3 + dx] = sI[(hy + dy) * 36 + hx + dx];
#pragma unroll
            for (int h = 0; h < 4; ++h) {
                int oc0 = s * 8 + h * 2;
                float a0 = bs1[oc0], a1 = bs1[oc0 + 1];
#pragma unroll
                for (int k = 0; k < 9; ++k) {
                    a0 += r[k] * ws1[oc0 * 9 + k];
                    a1 += r[k] * ws1[(oc0 + 1) * 9 + k];
                }
                a0 = fmaxf(a0, 0.f); a1 = fmaxf(a1, 0.f);
                pk[h] = (unsigned)f2bf(a0) | ((unsigned)f2bf(a1) << 16);
            }
        }
        *(uint4*)&Xs[hp * 72 + s * 8] = *(uint4*)pk;
    }
    __syncthreads();                             // Xs ready; pre phase-A reads done

    // phase B: stage conv3 weights into pre (K-loop reads only Xs/W2p)
    for (int idx = t; idx < 576; idx += 256) pre[idx] = w3c[idx];

    const int wn0 = w * 64;
    int pbase[4];
#pragma unroll
    for (int j = 0; j < 4; ++j) {
        int p = wn0 + j * 16 + l15;
        pbase[j] = (p >> 5) * 34 + (p & 31);
    }

    float4v acc[4][4];
#pragma unroll
    for (int i = 0; i < 4; ++i)
#pragma unroll
        for (int j = 0; j < 4; ++j)
#pragma unroll
            for (int r = 0; r < 4; ++r) acc[i][j][r] = 0.f;

    for (int tap = 0; tap < 9; ++tap) {
        int ky = tap / 3, kx = tap - ky * 3;
        const ushort_t* wp = W2p + tap * 4096;
#pragma unroll
        for (int c = 0; c < 2; ++c) {
            short8 af[4], bf[4];
#pragma unroll
            for (int i = 0; i < 4; ++i)
                af[i] = *(const short8*)&wp[(i * 16 + l15) * 64 + c * 32 + q * 8];
#pragma unroll
            for (int j = 0; j < 4; ++j)
                bf[j] = *(const short8*)&Xs[(pbase[j] + ky * 34 + kx) * 72 + c * 32 + q * 8];
#pragma unroll
            for (int i = 0; i < 4; ++i)
#pragma unroll
                for (int j = 0; j < 4; ++j)
                    acc[i][j] = __builtin_amdgcn_mfma_f32_16x16x32_bf16(
                        af[i], bf[j], acc[i][j], 0, 0, 0);
        }
    }
    __syncthreads();                             // w3c visible to all threads

    // epilogue: relu(conv2+b2), contract over oc against w3c -> 9 U planes
    float b2r[16];
#pragma unroll
    for (int i = 0; i < 4; ++i)
#pragma unroll
        for (int r = 0; r < 4; ++r) b2r[i * 4 + r] = b2[i * 16 + q * 4 + r];

#pragma unroll
    for (int j = 0; j < 4; ++j) {
        float u[9];
#pragma unroll
        for (int d = 0; d < 9; ++d) u[d] = 0.f;
#pragma unroll
        for (int i = 0; i < 4; ++i)
#pragma unroll
            for (int r = 0; r < 4; ++r) {
                int oc = i * 16 + q * 4 + r;
                float h = fmaxf(acc[i][j][r] + b2r[i * 4 + r], 0.f);
#pragma unroll
                for (int d = 0; d < 9; ++d) u[d] += h * pre[oc * 9 + d];
            }
#pragma unroll
        for (int d = 0; d < 9; ++d) {
            u[d] += __shfl_xor(u[d], 16, 64);
            u[d] += __shfl_xor(u[d], 32, 64);
        }
        int p = wn0 + j * 16 + l15;
        int y = y0 + (p >> 5), x = x0 + (p & 31);
#pragma unroll
        for (int dd = 0; dd < 3; ++dd) {
            int d = q + dd * 4;                 // q0:{0,4,8} q1:{1,5} q2:{2,6} q3:{3,7}
            if (d < 9)
                Uball[(size_t)d * NPIX + (size_t)y * IMG + x] = u[d];
        }
    }
}

// ---------------------------------------------------------------------------
// combine: out = relu( tmp1 + [bc3 + sum_d U_d(p+off(d))] + gather(g2T+gb4)/cnt )
// ---------------------------------------------------------------------------
__global__ __launch_bounds__(256) void k_combine(const float* __restrict__ in,
                                                 const float* __restrict__ proj,
                                                 const float* __restrict__ lamp,
                                                 const float* __restrict__ U,
                                                 const float* __restrict__ bc,
                                                 const float* __restrict__ g2T,
                                                 const float* __restrict__ gb4,
                                                 float* __restrict__ out) {
    int b = blockIdx.z;
    const float* inb = in + (size_t)b * NPIX;
    const float* prb = proj + (size_t)b * NPIX;
    const float* Ub = U + (size_t)b * 9 * NPIX;
    const float* g2b = g2T + (size_t)b * 64 * SN;
    int tx = threadIdx.x & 15, ty = threadIdx.x >> 4;
    int x = blockIdx.x * 16 + tx, y = blockIdx.y * 16 + ty;

    float acc = bc[0];
#pragma unroll
    for (int dy = 0; dy < 3; ++dy) {
        int yy = y + dy - 1;
#pragma unroll
        for (int dx = 0; dx < 3; ++dx) {
            int xx = x + dx - 1;
            if (yy >= 0 && yy < IMG && xx >= 0 && xx < IMG)
                acc += Ub[(size_t)(dy * 3 + dx) * NPIX + (size_t)yy * IMG + xx];
        }
    }

    float iv = inb[y * IMG + x], pv = prb[y * IMG + x];
    float tmp1 = iv + lamp[0] * (pv - iv);

    int pylo = (y >= 4) ? ((y - 4) >> 2) : 0;
    int pyhi = min(62, y >> 2);
    int pxlo = (x >= 4) ? ((x - 4) >> 2) : 0;
    int pxhi = min(62, x >> 2);
    float sum = 0.f;
    int cnt = 0;
    for (int py = pylo; py <= pyhi; ++py)
        for (int px = pxlo; px <= pxhi; ++px) {
            int pix = (y - 4 * py) * 8 + (x - 4 * px);
            sum += g2b[(size_t)pix * SN + (py * PH + px)] + gb4[pix];
            ++cnt;
        }
    float tmp3 = sum / (float)cnt;

    out[(size_t)b * NPIX + y * IMG + x] = fmaxf(tmp1 + acc + tmp3, 0.f);
}

// ---------------------------------------------------------------------------
extern "C" void kernel_launch(void* const* d_in, const int* in_sizes, int n_in,
                              void* d_out, int out_size, void* d_ws, size_t ws_size,
                              hipStream_t stream) {
    const float* input = (const float*)d_in[0];
    const float* proj  = (const float*)d_in[1];
    const float* adj   = (const float*)d_in[2];
    const float* lam   = (const float*)d_in[3];
    const float* cw1   = (const float*)d_in[4];
    const float* cb1   = (const float*)d_in[5];
    const float* cw2   = (const float*)d_in[6];
    const float* cb2   = (const float*)d_in[7];
    const float* cw3   = (const float*)d_in[8];
    const float* cb3   = (const float*)d_in[9];
    const float* gw3   = (const float*)d_in[10];
    const float* gb3   = (const float*)d_in[11];
    const float* gw4   = (const float*)d_in[12];
    const float* gb4   = (const float*)d_in[13];
    float* out = (float*)d_out;

    // ws layout (bytes) — adjb eliminated (both GEMMs convert adj inline):
    //   g2T fp32 [4][64][SN]                    @ 0          (4,096,000)
    //   pool @ 4,096,000:
    //     GCN phase: sup1T bf16 [4][128][SN]    @ pool+0     (4,096,000)
    //                g1T  fp32 [4][128][SN]     @ +4,096,000 (8,192,000)
    //                sup2T bf16 [4][64][SN]     @ +12,288,000(2,048,000)
    //     conv phase (reuses pool, stream-ordered after gemm<64>):
    //                U   fp32 [4][9][NPIX]      @ pool+0     (9,437,184)
    //                W2p bf16 [9][64][64]       @ +9,437,184 (73,728)
    char* base = (char*)d_ws;
    float*    g2T   = (float*)base;
    char*     pool  = base + 4096000;
    ushort_t* sup1T = (ushort_t*)pool;
    float*    g1T   = (float*)(pool + 4096000);
    ushort_t* sup2T = (ushort_t*)(pool + 4096000 + 8192000);
    float*    U     = (float*)pool;
    ushort_t* W2p   = (ushort_t*)(pool + 9437184);

    dim3 blk(256);

    hipMemsetAsync(g1T, 0, 8192000, stream);
    hipMemsetAsync(g2T, 0, 4096000, stream);

    // GCN branch (bf16 MFMA); both GEMMs convert adj fp32 -> bf16 inline
    k_sup1<<<dim3(125, 16, BATCH), blk, 0, stream>>>(input, gw3, sup1T);
    k_gemm_cvt<128><<<dim3(32, 8, BATCH), blk, 0, stream>>>(adj, sup1T, g1T);
    k_sup2<<<dim3(125, 8, BATCH), blk, 0, stream>>>(g1T, gb3, gw4, sup2T);
    k_gemm_cvt<64><<<dim3(32, 8, BATCH), blk, 0, stream>>>(adj, sup2T, g2T);

    // CNN branch + combine (pool reuse safe: stream-ordered after gemm<64>)
    k_prepack<<<dim3(144), blk, 0, stream>>>(cw2, W2p);
    k_conv2f<<<dim3(8, 32, BATCH), blk, 0, stream>>>(input, cw1, cb1, W2p, cb2, cw3, U);
    k_combine<<<dim3(16, 16, BATCH), blk, 0, stream>>>(
        input, proj, lam, U, cb3, g2T, gb4, out);
}

// Round 7
// 694.889 us; speedup vs baseline: 1.4276x; 1.4276x over previous
//
#include <hip/hip_runtime.h>

#define IMG   256
#define NPIX  65536          // 256*256
#define PH    63             // patches per side
#define NNODE 3969           // PH*PH
#define SN    4000           // padded node stride (mult of 32, 16B-aligned rows)
#define HID   64
#define GH    128
#define BATCH 4

typedef __attribute__((ext_vector_type(8))) short short8;
typedef __attribute__((ext_vector_type(4))) float float4v;
typedef unsigned short ushort_t;

__device__ inline ushort_t f2bf(float f) {
    union { float f; unsigned u; } v; v.f = f;
    unsigned r = v.u + 0x7FFF + ((v.u >> 16) & 1);   // RNE
    return (ushort_t)(r >> 16);
}

// ---------------------------------------------------------------------------
// adj fp32 [b][N][N] -> bf16 [b][N][SN], K-pad (3969..3999) zeroed
// fully coalesced: 256 threads stream a row (dword pairs), HBM-bound.
// ---------------------------------------------------------------------------
__global__ __launch_bounds__(256) void k_cvt_adj(const float* __restrict__ adj,
                                                 ushort_t* __restrict__ adjb) {
    int n = blockIdx.x, b = blockIdx.y;
    const float* src = adj + (size_t)(b * NNODE + n) * NNODE;
    unsigned* dst = (unsigned*)(adjb + (size_t)(b * NNODE + n) * SN);
    for (int c2 = threadIdx.x; c2 < SN / 2; c2 += 256) {
        int c = c2 * 2;
        float f0 = (c < NNODE) ? src[c] : 0.f;
        float f1 = (c + 1 < NNODE) ? src[c + 1] : 0.f;
        dst[c2] = (unsigned)f2bf(f0) | ((unsigned)f2bf(f1) << 16);
    }
}

// ---------------------------------------------------------------------------
// sup1T[b][g][n] = sum_pix patch[n][pix] * w3[pix][g]   (bf16 out, n-pad zeroed)
// input reads vectorized: 16x float4 per thread (rows 16B-aligned).
// ---------------------------------------------------------------------------
__global__ __launch_bounds__(256) void k_sup1(const float* __restrict__ in,
                                              const float* __restrict__ w3,
                                              ushort_t* __restrict__ sup1T) {
    int b = blockIdx.z;
    int g = blockIdx.y * 8 + (threadIdx.x >> 5);
    int n = blockIdx.x * 32 + (threadIdx.x & 31);
    ushort_t* dst = sup1T + (size_t)b * GH * SN + (size_t)g * SN + n;
    if (n >= NNODE) { *dst = 0; return; }
    int py = n / PH, px = n - py * PH;
    const float* base = in + (size_t)b * NPIX + (py * 4) * IMG + px * 4;
    float acc = 0.f;
#pragma unroll
    for (int i = 0; i < 8; ++i) {
        float4v v0 = *(const float4v*)&base[i * IMG];
        float4v v1 = *(const float4v*)&base[i * IMG + 4];
        const float* wrow = w3 + (i * 8) * GH + g;
#pragma unroll
        for (int j = 0; j < 4; ++j) acc += v0[j] * wrow[j * GH];
#pragma unroll
        for (int j = 0; j < 4; ++j) acc += v1[j] * wrow[(4 + j) * GH];
    }
    *dst = f2bf(acc);
}

// ---------------------------------------------------------------------------
// MFMA GEMM (transposed form): C[g][n] += sum_k supT[g][k] * adjb[n][k]
// BK=64 (two K=32 chunks per barrier pair). K split 8 ways (512-col disjoint
// chunks; ks=7 covers 385 cols + zeroed SN-pad) -> 1024 blocks = 4 blocks/CU
// for staging-latency hiding. Vector dwordx4 staging from bf16 adjb.
// C accumulated via atomics (memset upstream).
// ---------------------------------------------------------------------------
template <int G>
__global__ __launch_bounds__(256) void k_gemm_mfma(const ushort_t* __restrict__ adjb,
                                                   const ushort_t* __restrict__ supT,
                                                   float* __restrict__ C) {
    constexpr int FN = (G == 128) ? 4 : 2;
    const int b = blockIdx.z, ks = blockIdx.y;
    const int node0 = blockIdx.x * 128;
    const int t = threadIdx.x;
    const int lane = t & 63, w = t >> 6;
    const int l15 = lane & 15, q = lane >> 4;
    const int wm0 = (G == 128) ? (w & 1) * 64 : 0;
    const int wn0 = (G == 128) ? (w >> 1) * 64 : w * 32;

    __shared__ ushort_t Als[G][72];
    __shared__ ushort_t Bls[128][72];

    const int k0c = ks * 512;
    const int kend = (k0c + 512 < NNODE) ? (k0c + 512) : NNODE;
    const int kiters = (kend - k0c + 31) >> 5;       // 16, or 13 for ks=7
    const int npairs = (kiters + 1) >> 1;            // 8, or 7

    const ushort_t* Ab = supT + (size_t)b * G * SN;
    const ushort_t* Bb = adjb + (size_t)b * NNODE * SN;
    float* Cb = C + (size_t)b * G * SN;

    float4v acc[4][FN];
#pragma unroll
    for (int i = 0; i < 4; ++i)
#pragma unroll
        for (int j = 0; j < FN; ++j)
#pragma unroll
            for (int r = 0; r < 4; ++r) acc[i][j][r] = 0.f;

    for (int kp = 0; kp < npairs; ++kp) {
        const int kb0 = k0c + kp * 64;
        const bool has2 = (kp * 2 + 1 < kiters);     // wave-uniform
#pragma unroll
        for (int i = 0; i < G / 64; ++i) {
            int idx = t + i * 256;
            int r = idx >> 2, s = idx & 3;
            *(uint4*)&Als[r][s * 8] =
                *(const uint4*)&Ab[(size_t)r * SN + kb0 + s * 8];
        }
#pragma unroll
        for (int i = 0; i < 2; ++i) {
            int idx = t + i * 256;
            int r = idx >> 2, s = idx & 3;
            *(uint4*)&Bls[r][s * 8] =
                *(const uint4*)&Bb[(size_t)(node0 + r) * SN + kb0 + s * 8];
        }
        if (has2) {
#pragma unroll
            for (int i = 0; i < G / 64; ++i) {
                int idx = t + i * 256;
                int r = idx >> 2, s = idx & 3;
                *(uint4*)&Als[r][32 + s * 8] =
                    *(const uint4*)&Ab[(size_t)r * SN + kb0 + 32 + s * 8];
            }
#pragma unroll
            for (int i = 0; i < 2; ++i) {
                int idx = t + i * 256;
                int r = idx >> 2, s = idx & 3;
                *(uint4*)&Bls[r][32 + s * 8] =
                    *(const uint4*)&Bb[(size_t)(node0 + r) * SN + kb0 + 32 + s * 8];
            }
        }
        __syncthreads();
        {
            short8 af[4], bf[FN];
#pragma unroll
            for (int i = 0; i < 4; ++i)
                af[i] = *(const short8*)&Als[wm0 + i * 16 + l15][q * 8];
#pragma unroll
            for (int j = 0; j < FN; ++j)
                bf[j] = *(const short8*)&Bls[wn0 + j * 16 + l15][q * 8];
#pragma unroll
            for (int i = 0; i < 4; ++i)
#pragma unroll
                for (int j = 0; j < FN; ++j)
                    acc[i][j] = __builtin_amdgcn_mfma_f32_16x16x32_bf16(
                        af[i], bf[j], acc[i][j], 0, 0, 0);
        }
        if (has2) {
            short8 af[4], bf[FN];
#pragma unroll
            for (int i = 0; i < 4; ++i)
                af[i] = *(const short8*)&Als[wm0 + i * 16 + l15][32 + q * 8];
#pragma unroll
            for (int j = 0; j < FN; ++j)
                bf[j] = *(const short8*)&Bls[wn0 + j * 16 + l15][32 + q * 8];
#pragma unroll
            for (int i = 0; i < 4; ++i)
#pragma unroll
                for (int j = 0; j < FN; ++j)
                    acc[i][j] = __builtin_amdgcn_mfma_f32_16x16x32_bf16(
                        af[i], bf[j], acc[i][j], 0, 0, 0);
        }
        __syncthreads();
    }
#pragma unroll
    for (int i = 0; i < 4; ++i) {
        int gg = wm0 + i * 16 + q * 4;
#pragma unroll
        for (int j = 0; j < FN; ++j) {
            int nn = node0 + wn0 + j * 16 + l15;
            if (nn < NNODE) {
#pragma unroll
                for (int r = 0; r < 4; ++r)
                    unsafeAtomicAdd(&Cb[(size_t)(gg + r) * SN + nn], acc[i][j][r]);
            }
        }
    }
}

// ---------------------------------------------------------------------------
// sup2T[b][g][n] = sum_k relu(g1T[k][n] + gb3[k]) * w4[k][g]  (bf16, pad zeroed)
// ---------------------------------------------------------------------------
__global__ __launch_bounds__(256) void k_sup2(const float* __restrict__ g1T,
                                              const float* __restrict__ gb3,
                                              const float* __restrict__ w4,
                                              ushort_t* __restrict__ sup2T) {
    int b = blockIdx.z;
    int g = blockIdx.y * 8 + (threadIdx.x >> 5);
    int n = blockIdx.x * 32 + (threadIdx.x & 31);
    const float* gb = g1T + (size_t)b * GH * SN + n;
    float acc = 0.f;
#pragma unroll 8
    for (int k = 0; k < GH; ++k) {
        float v = fmaxf(gb[(size_t)k * SN] + gb3[k], 0.f);
        acc += v * w4[k * 64 + g];
    }
    sup2T[(size_t)b * 64 * SN + (size_t)g * SN + n] = (n < NNODE) ? f2bf(acc) : 0;
}

// ---------------------------------------------------------------------------
// prepack conv2 weights: cw2 [oc][ic][3][3] fp32 -> W2p [tap][oc][ic] bf16
// ---------------------------------------------------------------------------
__global__ __launch_bounds__(256) void k_prepack(const float* __restrict__ w,
                                                 ushort_t* __restrict__ W2p) {
    int idx = blockIdx.x * 256 + threadIdx.x;   // 9*64*64 = 36864
    if (idx >= 36864) return;
    int tap = idx >> 12, rem = idx & 4095;
    int oc = rem >> 6, ic = rem & 63;
    W2p[idx] = f2bf(w[(oc * 64 + ic) * 9 + tap]);
}

// ---------------------------------------------------------------------------
// conv2f: FUSED conv1 -> conv2(MFMA) -> conv3 channel-contraction.
// ---------------------------------------------------------------------------
__global__ __launch_bounds__(256) void k_conv2f(const float* __restrict__ in,
                                                const float* __restrict__ w1,
                                                const float* __restrict__ b1,
                                                const ushort_t* __restrict__ W2p,
                                                const float* __restrict__ b2,
                                                const float* __restrict__ w3c,
                                                float* __restrict__ U) {
    __shared__ ushort_t Xs[340 * 72];           // 48,960 B
    __shared__ float pre[1088];                 // 4,352 B (overlaid)
    const int b = blockIdx.z;
    const float* inb = in + (size_t)b * NPIX;
    float* Uball = U + (size_t)b * 9 * NPIX;
    const int t = threadIdx.x;
    const int lane = t & 63, w = t >> 6;
    const int l15 = lane & 15, q = lane >> 4;
    const int x0 = blockIdx.x * 32, y0 = blockIdx.y * 8;

    float* sI  = pre;                           // [12][36] input halo^2
    float* ws1 = pre + 432;                     // [576] conv1 weights
    float* bs1 = pre + 1008;                    // [64]  conv1 bias

    for (int idx = t; idx < 432; idx += 256) {
        int yy = idx / 36, xx = idx - yy * 36;
        int gy = y0 + yy - 2, gx = x0 + xx - 2;
        sI[idx] = (gy >= 0 && gy < IMG && gx >= 0 && gx < IMG) ? inb[gy * IMG + gx] : 0.f;
    }
    for (int idx = t; idx < 576; idx += 256) ws1[idx] = w1[idx];
    if (t < 64) bs1[t] = b1[t];
    __syncthreads();

    // conv1 -> Xs: 340 halo px x 64 ch (8 ch per (px,s) work item)
    for (int idx = t; idx < 2720; idx += 256) {
        int hp = idx >> 3, s = idx & 7;
        int hy = hp / 34, hx = hp - hy * 34;
        int gy = y0 + hy - 1, gx = x0 + hx - 1;
        unsigned pk[4] = {0u, 0u, 0u, 0u};
        if (gy >= 0 && gy < IMG && gx >= 0 && gx < IMG) {
            float r[9];
#pragma unroll
            for (int dy = 0; dy < 3; ++dy)
#pragma unroll
                for (int dx = 0; dx < 3; ++dx)
                    r[dy * 3 + dx] = sI[(hy + dy) * 36 + hx + dx];
#pragma unroll
            for (int h = 0; h < 4; ++h) {
                int oc0 = s * 8 + h * 2;
                float a0 = bs1[oc0], a1 = bs1[oc0 + 1];
#pragma unroll
                for (int k = 0; k < 9; ++k) {
                    a0 += r[k] * ws1[oc0 * 9 + k];
                    a1 += r[k] * ws1[(oc0 + 1) * 9 + k];
                }
                a0 = fmaxf(a0, 0.f); a1 = fmaxf(a1, 0.f);
                pk[h] = (unsigned)f2bf(a0) | ((unsigned)f2bf(a1) << 16);
            }
        }
        *(uint4*)&Xs[hp * 72 + s * 8] = *(uint4*)pk;
    }
    __syncthreads();                             // Xs ready; pre phase-A reads done

    // phase B: stage conv3 weights into pre (K-loop reads only Xs/W2p)
    for (int idx = t; idx < 576; idx += 256) pre[idx] = w3c[idx];

    const int wn0 = w * 64;
    int pbase[4];
#pragma unroll
    for (int j = 0; j < 4; ++j) {
        int p = wn0 + j * 16 + l15;
        pbase[j] = (p >> 5) * 34 + (p & 31);
    }

    float4v acc[4][4];
#pragma unroll
    for (int i = 0; i < 4; ++i)
#pragma unroll
        for (int j = 0; j < 4; ++j)
#pragma unroll
            for (int r = 0; r < 4; ++r) acc[i][j][r] = 0.f;

    for (int tap = 0; tap < 9; ++tap) {
        int ky = tap / 3, kx = tap - ky * 3;
        const ushort_t* wp = W2p + tap * 4096;
#pragma unroll
        for (int c = 0; c < 2; ++c) {
            short8 af[4], bf[4];
#pragma unroll
            for (int i = 0; i < 4; ++i)
                af[i] = *(const short8*)&wp[(i * 16 + l15) * 64 + c * 32 + q * 8];
#pragma unroll
            for (int j = 0; j < 4; ++j)
                bf[j] = *(const short8*)&Xs[(pbase[j] + ky * 34 + kx) * 72 + c * 32 + q * 8];
#pragma unroll
            for (int i = 0; i < 4; ++i)
#pragma unroll
                for (int j = 0; j < 4; ++j)
                    acc[i][j] = __builtin_amdgcn_mfma_f32_16x16x32_bf16(
                        af[i], bf[j], acc[i][j], 0, 0, 0);
        }
    }
    __syncthreads();                             // w3c visible to all threads

    // epilogue: relu(conv2+b2), contract over oc against w3c -> 9 U planes
    float b2r[16];
#pragma unroll
    for (int i = 0; i < 4; ++i)
#pragma unroll
        for (int r = 0; r < 4; ++r) b2r[i * 4 + r] = b2[i * 16 + q * 4 + r];

#pragma unroll
    for (int j = 0; j < 4; ++j) {
        float u[9];
#pragma unroll
        for (int d = 0; d < 9; ++d) u[d] = 0.f;
#pragma unroll
        for (int i = 0; i < 4; ++i)
#pragma unroll
            for (int r = 0; r < 4; ++r) {
                int oc = i * 16 + q * 4 + r;
                float h = fmaxf(acc[i][j][r] + b2r[i * 4 + r], 0.f);
#pragma unroll
                for (int d = 0; d < 9; ++d) u[d] += h * pre[oc * 9 + d];
            }
#pragma unroll
        for (int d = 0; d < 9; ++d) {
            u[d] += __shfl_xor(u[d], 16, 64);
            u[d] += __shfl_xor(u[d], 32, 64);
        }
        int p = wn0 + j * 16 + l15;
        int y = y0 + (p >> 5), x = x0 + (p & 31);
#pragma unroll
        for (int dd = 0; dd < 3; ++dd) {
            int d = q + dd * 4;                 // q0:{0,4,8} q1:{1,5} q2:{2,6} q3:{3,7}
            if (d < 9)
                Uball[(size_t)d * NPIX + (size_t)y * IMG + x] = u[d];
        }
    }
}

// ---------------------------------------------------------------------------
// combine: out = relu( tmp1 + [bc3 + sum_d U_d(p+off(d))] + gather(g2T+gb4)/cnt )
// ---------------------------------------------------------------------------
__global__ __launch_bounds__(256) void k_combine(const float* __restrict__ in,
                                                 const float* __restrict__ proj,
                                                 const float* __restrict__ lamp,
                                                 const float* __restrict__ U,
                                                 const float* __restrict__ bc,
                                                 const float* __restrict__ g2T,
                                                 const float* __restrict__ gb4,
                                                 float* __restrict__ out) {
    int b = blockIdx.z;
    const float* inb = in + (size_t)b * NPIX;
    const float* prb = proj + (size_t)b * NPIX;
    const float* Ub = U + (size_t)b * 9 * NPIX;
    const float* g2b = g2T + (size_t)b * 64 * SN;
    int tx = threadIdx.x & 15, ty = threadIdx.x >> 4;
    int x = blockIdx.x * 16 + tx, y = blockIdx.y * 16 + ty;

    float acc = bc[0];
#pragma unroll
    for (int dy = 0; dy < 3; ++dy) {
        int yy = y + dy - 1;
#pragma unroll
        for (int dx = 0; dx < 3; ++dx) {
            int xx = x + dx - 1;
            if (yy >= 0 && yy < IMG && xx >= 0 && xx < IMG)
                acc += Ub[(size_t)(dy * 3 + dx) * NPIX + (size_t)yy * IMG + xx];
        }
    }

    float iv = inb[y * IMG + x], pv = prb[y * IMG + x];
    float tmp1 = iv + lamp[0] * (pv - iv);

    int pylo = (y >= 4) ? ((y - 4) >> 2) : 0;
    int pyhi = min(62, y >> 2);
    int pxlo = (x >= 4) ? ((x - 4) >> 2) : 0;
    int pxhi = min(62, x >> 2);
    float sum = 0.f;
    int cnt = 0;
    for (int py = pylo; py <= pyhi; ++py)
        for (int px = pxlo; px <= pxhi; ++px) {
            int pix = (y - 4 * py) * 8 + (x - 4 * px);
            sum += g2b[(size_t)pix * SN + (py * PH + px)] + gb4[pix];
            ++cnt;
        }
    float tmp3 = sum / (float)cnt;

    out[(size_t)b * NPIX + y * IMG + x] = fmaxf(tmp1 + acc + tmp3, 0.f);
}

// ---------------------------------------------------------------------------
extern "C" void kernel_launch(void* const* d_in, const int* in_sizes, int n_in,
                              void* d_out, int out_size, void* d_ws, size_t ws_size,
                              hipStream_t stream) {
    const float* input = (const float*)d_in[0];
    const float* proj  = (const float*)d_in[1];
    const float* adj   = (const float*)d_in[2];
    const float* lam   = (const float*)d_in[3];
    const float* cw1   = (const float*)d_in[4];
    const float* cb1   = (const float*)d_in[5];
    const float* cw2   = (const float*)d_in[6];
    const float* cb2   = (const float*)d_in[7];
    const float* cw3   = (const float*)d_in[8];
    const float* cb3   = (const float*)d_in[9];
    const float* gw3   = (const float*)d_in[10];
    const float* gb3   = (const float*)d_in[11];
    const float* gw4   = (const float*)d_in[12];
    const float* gb4   = (const float*)d_in[13];
    float* out = (float*)d_out;

    // ws layout (bytes):
    //   g2T fp32 [4][64][SN]                    @ 0          (4,096,000)
    //   pool @ 4,096,000:
    //     GCN phase: adjb bf16 [4][N][SN]       (127,008,000)
    //                sup1T bf16 [4][128][SN]    (4,096,000)
    //                g1T  fp32 [4][128][SN]     (8,192,000)
    //                sup2T bf16 [4][64][SN]     (2,048,000)
    //     conv phase (reuses pool, stream-ordered after gemm<64>):
    //                U   fp32 [4][9][NPIX]      (9,437,184)
    //                W2p bf16 [9][64][64]       (73,728)
    char* base = (char*)d_ws;
    float*    g2T   = (float*)base;
    char*     pool  = base + 4096000;
    ushort_t* adjb  = (ushort_t*)pool;
    ushort_t* sup1T = (ushort_t*)(pool + 127008000);
    float*    g1T   = (float*)(pool + 127008000 + 4096000);
    ushort_t* sup2T = (ushort_t*)(pool + 127008000 + 4096000 + 8192000);
    float*    U     = (float*)pool;
    ushort_t* W2p   = (ushort_t*)(pool + 9437184);

    dim3 blk(256);

    hipMemsetAsync(g1T, 0, 8192000, stream);
    hipMemsetAsync(g2T, 0, 4096000, stream);

    // GCN branch (bf16 MFMA)
    k_cvt_adj<<<dim3(NNODE, BATCH), blk, 0, stream>>>(adj, adjb);
    k_sup1<<<dim3(125, 16, BATCH), blk, 0, stream>>>(input, gw3, sup1T);
    k_gemm_mfma<128><<<dim3(32, 8, BATCH), blk, 0, stream>>>(adjb, sup1T, g1T);
    k_sup2<<<dim3(125, 8, BATCH), blk, 0, stream>>>(g1T, gb3, gw4, sup2T);
    k_gemm_mfma<64><<<dim3(32, 8, BATCH), blk, 0, stream>>>(adjb, sup2T, g2T);

    // CNN branch + combine (pool reuse safe: stream-ordered after gemm<64>)
    k_prepack<<<dim3(144), blk, 0, stream>>>(cw2, W2p);
    k_conv2f<<<dim3(8, 32, BATCH), blk, 0, stream>>>(input, cw1, cb1, W2p, cb2, cw3, U);
    k_combine<<<dim3(16, 16, BATCH), blk, 0, stream>>>(
        input, proj, lam, U, cb3, g2T, gb4, out);
}

// Round 8
// 658.980 us; speedup vs baseline: 1.5054x; 1.0545x over previous
//
#include <hip/hip_runtime.h>

#define IMG   256
#define NPIX  65536          // 256*256
#define PH    63             // patches per side
#define NNODE 3969           // PH*PH
#define SN    4000           // padded node stride (mult of 32, 16B-aligned rows)
#define HID   64
#define GH    128
#define BATCH 4

typedef __attribute__((ext_vector_type(8))) short short8;
typedef __attribute__((ext_vector_type(4))) float float4v;
typedef unsigned short ushort_t;

__device__ inline ushort_t f2bf(float f) {
    union { float f; unsigned u; } v; v.f = f;
    unsigned r = v.u + 0x7FFF + ((v.u >> 16) & 1);   // RNE
    return (ushort_t)(r >> 16);
}

// ---------------------------------------------------------------------------
// adj fp32 [b][N][N] -> bf16 [b][N][SN], K-pad (3969..3999) zeroed
// fully coalesced: 256 threads stream a row (dword pairs), HBM-bound.
// ---------------------------------------------------------------------------
__global__ __launch_bounds__(256) void k_cvt_adj(const float* __restrict__ adj,
                                                 ushort_t* __restrict__ adjb) {
    int n = blockIdx.x, b = blockIdx.y;
    const float* src = adj + (size_t)(b * NNODE + n) * NNODE;
    unsigned* dst = (unsigned*)(adjb + (size_t)(b * NNODE + n) * SN);
    for (int c2 = threadIdx.x; c2 < SN / 2; c2 += 256) {
        int c = c2 * 2;
        float f0 = (c < NNODE) ? src[c] : 0.f;
        float f1 = (c + 1 < NNODE) ? src[c + 1] : 0.f;
        dst[c2] = (unsigned)f2bf(f0) | ((unsigned)f2bf(f1) << 16);
    }
}

// ---------------------------------------------------------------------------
// sup1T[b][g][n] = sum_pix patch[n][pix] * w3[pix][g]   (bf16 out, n-pad zeroed)
// input reads vectorized: 16x float4 per thread (rows 16B-aligned).
// ---------------------------------------------------------------------------
__global__ __launch_bounds__(256) void k_sup1(const float* __restrict__ in,
                                              const float* __restrict__ w3,
                                              ushort_t* __restrict__ sup1T) {
    int b = blockIdx.z;
    int g = blockIdx.y * 8 + (threadIdx.x >> 5);
    int n = blockIdx.x * 32 + (threadIdx.x & 31);
    ushort_t* dst = sup1T + (size_t)b * GH * SN + (size_t)g * SN + n;
    if (n >= NNODE) { *dst = 0; return; }
    int py = n / PH, px = n - py * PH;
    const float* base = in + (size_t)b * NPIX + (py * 4) * IMG + px * 4;
    float acc = 0.f;
#pragma unroll
    for (int i = 0; i < 8; ++i) {
        float4v v0 = *(const float4v*)&base[i * IMG];
        float4v v1 = *(const float4v*)&base[i * IMG + 4];
        const float* wrow = w3 + (i * 8) * GH + g;
#pragma unroll
        for (int j = 0; j < 4; ++j) acc += v0[j] * wrow[j * GH];
#pragma unroll
        for (int j = 0; j < 4; ++j) acc += v1[j] * wrow[(4 + j) * GH];
    }
    *dst = f2bf(acc);
}

// ---------------------------------------------------------------------------
// MFMA GEMM (transposed form): Cp[ks][g][n] = sum_{k in chunk ks} supT[g][k]*adjb[n][k]
// BK=64 (two K=32 chunks per barrier pair), K split 4 ways (992-col chunks).
// NO ATOMICS: each ks block writes its own partial buffer (plain coalesced
// stores); k_red4 sums the 4 partials downstream. No memset needed.
// ---------------------------------------------------------------------------
template <int G>
__global__ __launch_bounds__(256) void k_gemm_mfma(const ushort_t* __restrict__ adjb,
                                                   const ushort_t* __restrict__ supT,
                                                   float* __restrict__ Cp) {
    constexpr int FN = (G == 128) ? 4 : 2;
    const int b = blockIdx.z, ks = blockIdx.y;
    const int node0 = blockIdx.x * 128;
    const int t = threadIdx.x;
    const int lane = t & 63, w = t >> 6;
    const int l15 = lane & 15, q = lane >> 4;
    const int wm0 = (G == 128) ? (w & 1) * 64 : 0;
    const int wn0 = (G == 128) ? (w >> 1) * 64 : w * 32;

    __shared__ ushort_t Als[G][72];
    __shared__ ushort_t Bls[128][72];

    const int k0c = ks * 992;
    const int kend = (ks == 3) ? NNODE : k0c + 992;
    const int kiters = (kend - k0c + 31) >> 5;       // 31 (ks<3) or 32 (ks=3)
    const int npairs = (kiters + 1) >> 1;            // 16

    const ushort_t* Ab = supT + (size_t)b * G * SN;
    const ushort_t* Bb = adjb + (size_t)b * NNODE * SN;
    float* Cb = Cp + (size_t)ks * BATCH * G * SN + (size_t)b * G * SN;

    float4v acc[4][FN];
#pragma unroll
    for (int i = 0; i < 4; ++i)
#pragma unroll
        for (int j = 0; j < FN; ++j)
#pragma unroll
            for (int r = 0; r < 4; ++r) acc[i][j][r] = 0.f;

    for (int kp = 0; kp < npairs; ++kp) {
        const int kb0 = k0c + kp * 64;
        const bool has2 = (kp * 2 + 1 < kiters);     // wave-uniform
#pragma unroll
        for (int i = 0; i < G / 64; ++i) {
            int idx = t + i * 256;
            int r = idx >> 2, s = idx & 3;
            *(uint4*)&Als[r][s * 8] =
                *(const uint4*)&Ab[(size_t)r * SN + kb0 + s * 8];
        }
#pragma unroll
        for (int i = 0; i < 2; ++i) {
            int idx = t + i * 256;
            int r = idx >> 2, s = idx & 3;
            *(uint4*)&Bls[r][s * 8] =
                *(const uint4*)&Bb[(size_t)(node0 + r) * SN + kb0 + s * 8];
        }
        if (has2) {
#pragma unroll
            for (int i = 0; i < G / 64; ++i) {
                int idx = t + i * 256;
                int r = idx >> 2, s = idx & 3;
                *(uint4*)&Als[r][32 + s * 8] =
                    *(const uint4*)&Ab[(size_t)r * SN + kb0 + 32 + s * 8];
            }
#pragma unroll
            for (int i = 0; i < 2; ++i) {
                int idx = t + i * 256;
                int r = idx >> 2, s = idx & 3;
                *(uint4*)&Bls[r][32 + s * 8] =
                    *(const uint4*)&Bb[(size_t)(node0 + r) * SN + kb0 + 32 + s * 8];
            }
        }
        __syncthreads();
        {
            short8 af[4], bf[FN];
#pragma unroll
            for (int i = 0; i < 4; ++i)
                af[i] = *(const short8*)&Als[wm0 + i * 16 + l15][q * 8];
#pragma unroll
            for (int j = 0; j < FN; ++j)
                bf[j] = *(const short8*)&Bls[wn0 + j * 16 + l15][q * 8];
#pragma unroll
            for (int i = 0; i < 4; ++i)
#pragma unroll
                for (int j = 0; j < FN; ++j)
                    acc[i][j] = __builtin_amdgcn_mfma_f32_16x16x32_bf16(
                        af[i], bf[j], acc[i][j], 0, 0, 0);
        }
        if (has2) {
            short8 af[4], bf[FN];
#pragma unroll
            for (int i = 0; i < 4; ++i)
                af[i] = *(const short8*)&Als[wm0 + i * 16 + l15][32 + q * 8];
#pragma unroll
            for (int j = 0; j < FN; ++j)
                bf[j] = *(const short8*)&Bls[wn0 + j * 16 + l15][32 + q * 8];
#pragma unroll
            for (int i = 0; i < 4; ++i)
#pragma unroll
                for (int j = 0; j < FN; ++j)
                    acc[i][j] = __builtin_amdgcn_mfma_f32_16x16x32_bf16(
                        af[i], bf[j], acc[i][j], 0, 0, 0);
        }
        __syncthreads();
    }
    // plain coalesced stores (64B contiguous per quarter-wave per (i,j,r))
#pragma unroll
    for (int i = 0; i < 4; ++i) {
        int gg = wm0 + i * 16 + q * 4;
#pragma unroll
        for (int j = 0; j < FN; ++j) {
            int nn = node0 + wn0 + j * 16 + l15;
            if (nn < NNODE) {
#pragma unroll
                for (int r = 0; r < 4; ++r)
                    Cb[(size_t)(gg + r) * SN + nn] = acc[i][j][r];
            }
        }
    }
}

// ---------------------------------------------------------------------------
// k_red4: out[i] = sum_{ks<4} in[ks*q4*4 floats + i]  (float4-vectorized)
// n4/q4 in float4 units. Pad columns sum poison/NaN -> consumed only by
// guarded-discard lanes downstream.
// ---------------------------------------------------------------------------
__global__ __launch_bounds__(256) void k_red4(const float* __restrict__ in,
                                              float* __restrict__ out,
                                              int n4, int q4) {
    int i = blockIdx.x * 256 + threadIdx.x;
    if (i >= n4) return;
    const float4v* in4 = (const float4v*)in;
    float4v a = in4[i];
    float4v b = in4[i + q4];
    float4v c = in4[i + 2 * q4];
    float4v d = in4[i + 3 * q4];
#pragma unroll
    for (int r = 0; r < 4; ++r) a[r] = (a[r] + b[r]) + (c[r] + d[r]);
    ((float4v*)out)[i] = a;
}

// ---------------------------------------------------------------------------
// sup2T[b][g][n] = sum_k relu(g1T[k][n] + gb3[k]) * w4[k][g]  (bf16, pad zeroed)
// ---------------------------------------------------------------------------
__global__ __launch_bounds__(256) void k_sup2(const float* __restrict__ g1T,
                                              const float* __restrict__ gb3,
                                              const float* __restrict__ w4,
                                              ushort_t* __restrict__ sup2T) {
    int b = blockIdx.z;
    int g = blockIdx.y * 8 + (threadIdx.x >> 5);
    int n = blockIdx.x * 32 + (threadIdx.x & 31);
    const float* gb = g1T + (size_t)b * GH * SN + n;
    float acc = 0.f;
#pragma unroll 8
    for (int k = 0; k < GH; ++k) {
        float v = fmaxf(gb[(size_t)k * SN] + gb3[k], 0.f);
        acc += v * w4[k * 64 + g];
    }
    sup2T[(size_t)b * 64 * SN + (size_t)g * SN + n] = (n < NNODE) ? f2bf(acc) : 0;
}

// ---------------------------------------------------------------------------
// prepack conv2 weights: cw2 [oc][ic][3][3] fp32 -> W2p [tap][oc][ic] bf16
// ---------------------------------------------------------------------------
__global__ __launch_bounds__(256) void k_prepack(const float* __restrict__ w,
                                                 ushort_t* __restrict__ W2p) {
    int idx = blockIdx.x * 256 + threadIdx.x;   // 9*64*64 = 36864
    if (idx >= 36864) return;
    int tap = idx >> 12, rem = idx & 4095;
    int oc = rem >> 6, ic = rem & 63;
    W2p[idx] = f2bf(w[(oc * 64 + ic) * 9 + tap]);
}

// ---------------------------------------------------------------------------
// conv2f: FUSED conv1 -> conv2(MFMA) -> conv3 channel-contraction.
// ---------------------------------------------------------------------------
__global__ __launch_bounds__(256) void k_conv2f(const float* __restrict__ in,
                                                const float* __restrict__ w1,
                                                const float* __restrict__ b1,
                                                const ushort_t* __restrict__ W2p,
                                                const float* __restrict__ b2,
                                                const float* __restrict__ w3c,
                                                float* __restrict__ U) {
    __shared__ ushort_t Xs[340 * 72];           // 48,960 B
    __shared__ float pre[1088];                 // 4,352 B (overlaid)
    const int b = blockIdx.z;
    const float* inb = in + (size_t)b * NPIX;
    float* Uball = U + (size_t)b * 9 * NPIX;
    const int t = threadIdx.x;
    const int lane = t & 63, w = t >> 6;
    const int l15 = lane & 15, q = lane >> 4;
    const int x0 = blockIdx.x * 32, y0 = blockIdx.y * 8;

    float* sI  = pre;                           // [12][36] input halo^2
    float* ws1 = pre + 432;                     // [576] conv1 weights
    float* bs1 = pre + 1008;                    // [64]  conv1 bias

    for (int idx = t; idx < 432; idx += 256) {
        int yy = idx / 36, xx = idx - yy * 36;
        int gy = y0 + yy - 2, gx = x0 + xx - 2;
        sI[idx] = (gy >= 0 && gy < IMG && gx >= 0 && gx < IMG) ? inb[gy * IMG + gx] : 0.f;
    }
    for (int idx = t; idx < 576; idx += 256) ws1[idx] = w1[idx];
    if (t < 64) bs1[t] = b1[t];
    __syncthreads();

    // conv1 -> Xs: 340 halo px x 64 ch (8 ch per (px,s) work item)
    for (int idx = t; idx < 2720; idx += 256) {
        int hp = idx >> 3, s = idx & 7;
        int hy = hp / 34, hx = hp - hy * 34;
        int gy = y0 + hy - 1, gx = x0 + hx - 1;
        unsigned pk[4] = {0u, 0u, 0u, 0u};
        if (gy >= 0 && gy < IMG && gx >= 0 && gx < IMG) {
            float r[9];
#pragma unroll
            for (int dy = 0; dy < 3; ++dy)
#pragma unroll
                for (int dx = 0; dx < 3; ++dx)
                    r[dy * 3 + dx] = sI[(hy + dy) * 36 + hx + dx];
#pragma unroll
            for (int h = 0; h < 4; ++h) {
                int oc0 = s * 8 + h * 2;
                float a0 = bs1[oc0], a1 = bs1[oc0 + 1];
#pragma unroll
                for (int k = 0; k < 9; ++k) {
                    a0 += r[k] * ws1[oc0 * 9 + k];
                    a1 += r[k] * ws1[(oc0 + 1) * 9 + k];
                }
                a0 = fmaxf(a0, 0.f); a1 = fmaxf(a1, 0.f);
                pk[h] = (unsigned)f2bf(a0) | ((unsigned)f2bf(a1) << 16);
            }
        }
        *(uint4*)&Xs[hp * 72 + s * 8] = *(uint4*)pk;
    }
    __syncthreads();                             // Xs ready; pre phase-A reads done

    // phase B: stage conv3 weights into pre (K-loop reads only Xs/W2p)
    for (int idx = t; idx < 576; idx += 256) pre[idx] = w3c[idx];

    const int wn0 = w * 64;
    int pbase[4];
#pragma unroll
    for (int j = 0; j < 4; ++j) {
        int p = wn0 + j * 16 + l15;
        pbase[j] = (p >> 5) * 34 + (p & 31);
    }

    float4v acc[4][4];
#pragma unroll
    for (int i = 0; i < 4; ++i)
#pragma unroll
        for (int j = 0; j < 4; ++j)
#pragma unroll
            for (int r = 0; r < 4; ++r) acc[i][j][r] = 0.f;

    for (int tap = 0; tap < 9; ++tap) {
        int ky = tap / 3, kx = tap - ky * 3;
        const ushort_t* wp = W2p + tap * 4096;
#pragma unroll
        for (int c = 0; c < 2; ++c) {
            short8 af[4], bf[4];
#pragma unroll
            for (int i = 0; i < 4; ++i)
                af[i] = *(const short8*)&wp[(i * 16 + l15) * 64 + c * 32 + q * 8];
#pragma unroll
            for (int j = 0; j < 4; ++j)
                bf[j] = *(const short8*)&Xs[(pbase[j] + ky * 34 + kx) * 72 + c * 32 + q * 8];
#pragma unroll
            for (int i = 0; i < 4; ++i)
#pragma unroll
                for (int j = 0; j < 4; ++j)
                    acc[i][j] = __builtin_amdgcn_mfma_f32_16x16x32_bf16(
                        af[i], bf[j], acc[i][j], 0, 0, 0);
        }
    }
    __syncthreads();                             // w3c visible to all threads

    // epilogue: relu(conv2+b2), contract over oc against w3c -> 9 U planes
    float b2r[16];
#pragma unroll
    for (int i = 0; i < 4; ++i)
#pragma unroll
        for (int r = 0; r < 4; ++r) b2r[i * 4 + r] = b2[i * 16 + q * 4 + r];

#pragma unroll
    for (int j = 0; j < 4; ++j) {
        float u[9];
#pragma unroll
        for (int d = 0; d < 9; ++d) u[d] = 0.f;
#pragma unroll
        for (int i = 0; i < 4; ++i)
#pragma unroll
            for (int r = 0; r < 4; ++r) {
                int oc = i * 16 + q * 4 + r;
                float h = fmaxf(acc[i][j][r] + b2r[i * 4 + r], 0.f);
#pragma unroll
                for (int d = 0; d < 9; ++d) u[d] += h * pre[oc * 9 + d];
            }
#pragma unroll
        for (int d = 0; d < 9; ++d) {
            u[d] += __shfl_xor(u[d], 16, 64);
            u[d] += __shfl_xor(u[d], 32, 64);
        }
        int p = wn0 + j * 16 + l15;
        int y = y0 + (p >> 5), x = x0 + (p & 31);
#pragma unroll
        for (int dd = 0; dd < 3; ++dd) {
            int d = q + dd * 4;                 // q0:{0,4,8} q1:{1,5} q2:{2,6} q3:{3,7}
            if (d < 9)
                Uball[(size_t)d * NPIX + (size_t)y * IMG + x] = u[d];
        }
    }
}

// ---------------------------------------------------------------------------
// combine: out = relu( tmp1 + [bc3 + sum_d U_d(p+off(d))] + gather(g2T+gb4)/cnt )
// ---------------------------------------------------------------------------
__global__ __launch_bounds__(256) void k_combine(const float* __restrict__ in,
                                                 const float* __restrict__ proj,
                                                 const float* __restrict__ lamp,
                                                 const float* __restrict__ U,
                                                 const float* __restrict__ bc,
                                                 const float* __restrict__ g2T,
                                                 const float* __restrict__ gb4,
                                                 float* __restrict__ out) {
    int b = blockIdx.z;
    const float* inb = in + (size_t)b * NPIX;
    const float* prb = proj + (size_t)b * NPIX;
    const float* Ub = U + (size_t)b * 9 * NPIX;
    const float* g2b = g2T + (size_t)b * 64 * SN;
    int tx = threadIdx.x & 15, ty = threadIdx.x >> 4;
    int x = blockIdx.x * 16 + tx, y = blockIdx.y * 16 + ty;

    float acc = bc[0];
#pragma unroll
    for (int dy = 0; dy < 3; ++dy) {
        int yy = y + dy - 1;
#pragma unroll
        for (int dx = 0; dx < 3; ++dx) {
            int xx = x + dx - 1;
            if (yy >= 0 && yy < IMG && xx >= 0 && xx < IMG)
                acc += Ub[(size_t)(dy * 3 + dx) * NPIX + (size_t)yy * IMG + xx];
        }
    }

    float iv = inb[y * IMG + x], pv = prb[y * IMG + x];
    float tmp1 = iv + lamp[0] * (pv - iv);

    int pylo = (y >= 4) ? ((y - 4) >> 2) : 0;
    int pyhi = min(62, y >> 2);
    int pxlo = (x >= 4) ? ((x - 4) >> 2) : 0;
    int pxhi = min(62, x >> 2);
    float sum = 0.f;
    int cnt = 0;
    for (int py = pylo; py <= pyhi; ++py)
        for (int px = pxlo; px <= pxhi; ++px) {
            int pix = (y - 4 * py) * 8 + (x - 4 * px);
            sum += g2b[(size_t)pix * SN + (py * PH + px)] + gb4[pix];
            ++cnt;
        }
    float tmp3 = sum / (float)cnt;

    out[(size_t)b * NPIX + y * IMG + x] = fmaxf(tmp1 + acc + tmp3, 0.f);
}

// ---------------------------------------------------------------------------
extern "C" void kernel_launch(void* const* d_in, const int* in_sizes, int n_in,
                              void* d_out, int out_size, void* d_ws, size_t ws_size,
                              hipStream_t stream) {
    const float* input = (const float*)d_in[0];
    const float* proj  = (const float*)d_in[1];
    const float* adj   = (const float*)d_in[2];
    const float* lam   = (const float*)d_in[3];
    const float* cw1   = (const float*)d_in[4];
    const float* cb1   = (const float*)d_in[5];
    const float* cw2   = (const float*)d_in[6];
    const float* cb2   = (const float*)d_in[7];
    const float* cw3   = (const float*)d_in[8];
    const float* cb3   = (const float*)d_in[9];
    const float* gw3   = (const float*)d_in[10];
    const float* gb3   = (const float*)d_in[11];
    const float* gw4   = (const float*)d_in[12];
    const float* gb4   = (const float*)d_in[13];
    float* out = (float*)d_out;

    // ws layout (bytes), total 178,208,000 (harness poison-fill shows ~1 GB
    // workspace, so this fits):
    //   g2T fp32 [4][64][SN]                    @ 0            (4,096,000)
    //   pool @ 4,096,000:
    //     adjb  bf16 [4][N][SN]                 @ +0           (127,008,000)
    //     sup1T bf16 [4][128][SN]               @ +127,008,000 (4,096,000)
    //     g1T   fp32 [4][128][SN]               @ +131,104,000 (8,192,000)
    //     sup2T bf16 [4][64][SN]                @ +139,296,000 (2,048,000)
    //     shared @ +141,344,000                                (32,768,000):
    //       g1P fp32 [4ks][4][128][SN]  (32,768,000)  dead after red128
    //       g2P fp32 [4ks][4][64][SN]   (16,384,000)  alias g1P, dead after red64
    //       U   fp32 [4][9][NPIX]       (9,437,184)   alias g2P (after red64)
    //       W2p bf16 [9][64][64]        (73,728)      @ shared+9,437,184
    char* base = (char*)d_ws;
    float*    g2T   = (float*)base;
    char*     pool  = base + 4096000;
    ushort_t* adjb  = (ushort_t*)pool;
    ushort_t* sup1T = (ushort_t*)(pool + 127008000);
    float*    g1T   = (float*)(pool + 131104000);
    ushort_t* sup2T = (ushort_t*)(pool + 139296000);
    char*     shared = pool + 141344000;
    float*    g1P   = (float*)shared;
    float*    g2P   = (float*)shared;            // alias: g1P dead after red128
    float*    U     = (float*)shared;            // alias: g2P dead after red64
    ushort_t* W2p   = (ushort_t*)(shared + 9437184);

    dim3 blk(256);

    // GCN branch (bf16 MFMA, atomic-free partial accumulation)
    k_cvt_adj<<<dim3(NNODE, BATCH), blk, 0, stream>>>(adj, adjb);
    k_sup1<<<dim3(125, 16, BATCH), blk, 0, stream>>>(input, gw3, sup1T);
    k_gemm_mfma<128><<<dim3(32, 4, BATCH), blk, 0, stream>>>(adjb, sup1T, g1P);
    k_red4<<<dim3(2000), blk, 0, stream>>>(g1P, g1T, 512000, 512000);
    k_sup2<<<dim3(125, 8, BATCH), blk, 0, stream>>>(g1T, gb3, gw4, sup2T);
    k_gemm_mfma<64><<<dim3(32, 4, BATCH), blk, 0, stream>>>(adjb, sup2T, g2P);
    k_red4<<<dim3(1000), blk, 0, stream>>>(g2P, g2T, 256000, 256000);

    // CNN branch + combine (prepack/conv2f after red64: W2p/U alias g1P/g2P)
    k_prepack<<<dim3(144), blk, 0, stream>>>(cw2, W2p);
    k_conv2f<<<dim3(8, 32, BATCH), blk, 0, stream>>>(input, cw1, cb1, W2p, cb2, cw3, U);
    k_combine<<<dim3(16, 16, BATCH), blk, 0, stream>>>(
        input, proj, lam, U, cb3, g2T, gb4, out);
}

// Round 9
// 647.020 us; speedup vs baseline: 1.5332x; 1.0185x over previous
//
#include <hip/hip_runtime.h>

#define IMG   256
#define NPIX  65536          // 256*256
#define PH    63             // patches per side
#define NNODE 3969           // PH*PH
#define SN    4000           // padded node stride (mult of 32, 16B-aligned rows)
#define HID   64
#define GH    128
#define BATCH 4

typedef __attribute__((ext_vector_type(8))) short short8;
typedef __attribute__((ext_vector_type(4))) float float4v;
typedef unsigned short ushort_t;

__device__ inline ushort_t f2bf(float f) {
    union { float f; unsigned u; } v; v.f = f;
    unsigned r = v.u + 0x7FFF + ((v.u >> 16) & 1);   // RNE
    return (ushort_t)(r >> 16);
}

// ---------------------------------------------------------------------------
// adj fp32 [b][N][N] -> bf16 [b][N][SN], K-pad (3969..3999) zeroed
// fully coalesced: 256 threads stream a row (dword pairs), HBM-bound.
// ---------------------------------------------------------------------------
__global__ __launch_bounds__(256) void k_cvt_adj(const float* __restrict__ adj,
                                                 ushort_t* __restrict__ adjb) {
    int n = blockIdx.x, b = blockIdx.y;
    const float* src = adj + (size_t)(b * NNODE + n) * NNODE;
    unsigned* dst = (unsigned*)(adjb + (size_t)(b * NNODE + n) * SN);
    for (int c2 = threadIdx.x; c2 < SN / 2; c2 += 256) {
        int c = c2 * 2;
        float f0 = (c < NNODE) ? src[c] : 0.f;
        float f1 = (c + 1 < NNODE) ? src[c + 1] : 0.f;
        dst[c2] = (unsigned)f2bf(f0) | ((unsigned)f2bf(f1) << 16);
    }
}

// ---------------------------------------------------------------------------
// sup1T[b][g][n] = sum_pix patch[n][pix] * w3[pix][g]   (bf16 out, n-pad zeroed)
// input reads vectorized: 16x float4 per thread (rows 16B-aligned).
// ---------------------------------------------------------------------------
__global__ __launch_bounds__(256) void k_sup1(const float* __restrict__ in,
                                              const float* __restrict__ w3,
                                              ushort_t* __restrict__ sup1T) {
    int b = blockIdx.z;
    int g = blockIdx.y * 8 + (threadIdx.x >> 5);
    int n = blockIdx.x * 32 + (threadIdx.x & 31);
    ushort_t* dst = sup1T + (size_t)b * GH * SN + (size_t)g * SN + n;
    if (n >= NNODE) { *dst = 0; return; }
    int py = n / PH, px = n - py * PH;
    const float* base = in + (size_t)b * NPIX + (py * 4) * IMG + px * 4;
    float acc = 0.f;
#pragma unroll
    for (int i = 0; i < 8; ++i) {
        float4v v0 = *(const float4v*)&base[i * IMG];
        float4v v1 = *(const float4v*)&base[i * IMG + 4];
        const float* wrow = w3 + (i * 8) * GH + g;
#pragma unroll
        for (int j = 0; j < 4; ++j) acc += v0[j] * wrow[j * GH];
#pragma unroll
        for (int j = 0; j < 4; ++j) acc += v1[j] * wrow[(4 + j) * GH];
    }
    *dst = f2bf(acc);
}

// ---------------------------------------------------------------------------
// MFMA GEMM (transposed form): Cp[ks][g][n] = sum_{k in chunk ks} supT[g][k]*adjb[n][k]
// BK=64 (two K=32 chunks per barrier pair), K split 4 ways (992-col chunks).
// NODE TILE 64 (was 128): grid 63x4x4 = 1008 blocks = ~4 blocks/CU for
// staging-latency hiding (atomic confound removed in round 8 -> clean TLP
// test). Extra cost: A (supT, L3-resident 16/8 MB) read 2x. Tail node rows
// >= NNODE are clamp-staged (no OOB/NaN ingestion) and store-guarded.
// NO ATOMICS: per-ks partial buffers, k_red4 sums downstream.
// ---------------------------------------------------------------------------
template <int G>
__global__ __launch_bounds__(256) void k_gemm_mfma(const ushort_t* __restrict__ adjb,
                                                   const ushort_t* __restrict__ supT,
                                                   float* __restrict__ Cp) {
    constexpr int FN = (G == 128) ? 2 : 1;           // n-fragments per wave
    const int b = blockIdx.z, ks = blockIdx.y;
    const int node0 = blockIdx.x * 64;
    const int t = threadIdx.x;
    const int lane = t & 63, w = t >> 6;
    const int l15 = lane & 15, q = lane >> 4;
    const int wm0 = (G == 128) ? (w & 1) * 64 : 0;
    const int wn0 = (G == 128) ? (w >> 1) * 32 : w * 16;

    __shared__ ushort_t Als[G][72];
    __shared__ ushort_t Bls[64][72];

    const int k0c = ks * 992;
    const int kend = (ks == 3) ? NNODE : k0c + 992;
    const int kiters = (kend - k0c + 31) >> 5;       // 31 (ks<3) or 32 (ks=3)
    const int npairs = (kiters + 1) >> 1;            // 16

    const ushort_t* Ab = supT + (size_t)b * G * SN;
    const ushort_t* Bb = adjb + (size_t)b * NNODE * SN;
    float* Cb = Cp + (size_t)ks * BATCH * G * SN + (size_t)b * G * SN;

    // B staging coords: 256 threads cover 64 rows x 4 16B-chunks
    const int br = t >> 2;                           // 0..63
    const int bs = t & 3;                            // 0..3
    const int brow = (node0 + br < NNODE) ? (node0 + br) : (NNODE - 1);  // clamp

    float4v acc[4][FN];
#pragma unroll
    for (int i = 0; i < 4; ++i)
#pragma unroll
        for (int j = 0; j < FN; ++j)
#pragma unroll
            for (int r = 0; r < 4; ++r) acc[i][j][r] = 0.f;

    for (int kp = 0; kp < npairs; ++kp) {
        const int kb0 = k0c + kp * 64;
        const bool has2 = (kp * 2 + 1 < kiters);     // wave-uniform
        // ---- A staging ----
#pragma unroll
        for (int i = 0; i < G / 64; ++i) {
            int idx = t + i * 256;
            int r = idx >> 2, s = idx & 3;
            *(uint4*)&Als[r][s * 8] =
                *(const uint4*)&Ab[(size_t)r * SN + kb0 + s * 8];
        }
        if (has2) {
#pragma unroll
            for (int i = 0; i < G / 64; ++i) {
                int idx = t + i * 256;
                int r = idx >> 2, s = idx & 3;
                *(uint4*)&Als[r][32 + s * 8] =
                    *(const uint4*)&Ab[(size_t)r * SN + kb0 + 32 + s * 8];
            }
        }
        // ---- B staging (clamped tail rows; discarded at store) ----
        *(uint4*)&Bls[br][bs * 8] =
            *(const uint4*)&Bb[(size_t)brow * SN + kb0 + bs * 8];
        if (has2)
            *(uint4*)&Bls[br][32 + bs * 8] =
                *(const uint4*)&Bb[(size_t)brow * SN + kb0 + 32 + bs * 8];
        __syncthreads();
        {
            short8 af[4], bf[FN];
#pragma unroll
            for (int i = 0; i < 4; ++i)
                af[i] = *(const short8*)&Als[wm0 + i * 16 + l15][q * 8];
#pragma unroll
            for (int j = 0; j < FN; ++j)
                bf[j] = *(const short8*)&Bls[wn0 + j * 16 + l15][q * 8];
#pragma unroll
            for (int i = 0; i < 4; ++i)
#pragma unroll
                for (int j = 0; j < FN; ++j)
                    acc[i][j] = __builtin_amdgcn_mfma_f32_16x16x32_bf16(
                        af[i], bf[j], acc[i][j], 0, 0, 0);
        }
        if (has2) {
            short8 af[4], bf[FN];
#pragma unroll
            for (int i = 0; i < 4; ++i)
                af[i] = *(const short8*)&Als[wm0 + i * 16 + l15][32 + q * 8];
#pragma unroll
            for (int j = 0; j < FN; ++j)
                bf[j] = *(const short8*)&Bls[wn0 + j * 16 + l15][32 + q * 8];
#pragma unroll
            for (int i = 0; i < 4; ++i)
#pragma unroll
                for (int j = 0; j < FN; ++j)
                    acc[i][j] = __builtin_amdgcn_mfma_f32_16x16x32_bf16(
                        af[i], bf[j], acc[i][j], 0, 0, 0);
        }
        __syncthreads();
    }
    // plain coalesced stores (64B contiguous per quarter-wave per (i,j,r))
#pragma unroll
    for (int i = 0; i < 4; ++i) {
        int gg = wm0 + i * 16 + q * 4;
#pragma unroll
        for (int j = 0; j < FN; ++j) {
            int nn = node0 + wn0 + j * 16 + l15;
            if (nn < NNODE) {
#pragma unroll
                for (int r = 0; r < 4; ++r)
                    Cb[(size_t)(gg + r) * SN + nn] = acc[i][j][r];
            }
        }
    }
}

// ---------------------------------------------------------------------------
// k_red4: out[i] = sum_{ks<4} in[ks*q4*4 floats + i]  (float4-vectorized)
// n4/q4 in float4 units. Pad columns sum poison/NaN -> consumed only by
// guarded-discard lanes downstream.
// ---------------------------------------------------------------------------
__global__ __launch_bounds__(256) void k_red4(const float* __restrict__ in,
                                              float* __restrict__ out,
                                              int n4, int q4) {
    int i = blockIdx.x * 256 + threadIdx.x;
    if (i >= n4) return;
    const float4v* in4 = (const float4v*)in;
    float4v a = in4[i];
    float4v b = in4[i + q4];
    float4v c = in4[i + 2 * q4];
    float4v d = in4[i + 3 * q4];
#pragma unroll
    for (int r = 0; r < 4; ++r) a[r] = (a[r] + b[r]) + (c[r] + d[r]);
    ((float4v*)out)[i] = a;
}

// ---------------------------------------------------------------------------
// sup2T[b][g][n] = sum_k relu(g1T[k][n] + gb3[k]) * w4[k][g]  (bf16, pad zeroed)
// ---------------------------------------------------------------------------
__global__ __launch_bounds__(256) void k_sup2(const float* __restrict__ g1T,
                                              const float* __restrict__ gb3,
                                              const float* __restrict__ w4,
                                              ushort_t* __restrict__ sup2T) {
    int b = blockIdx.z;
    int g = blockIdx.y * 8 + (threadIdx.x >> 5);
    int n = blockIdx.x * 32 + (threadIdx.x & 31);
    const float* gb = g1T + (size_t)b * GH * SN + n;
    float acc = 0.f;
#pragma unroll 8
    for (int k = 0; k < GH; ++k) {
        float v = fmaxf(gb[(size_t)k * SN] + gb3[k], 0.f);
        acc += v * w4[k * 64 + g];
    }
    sup2T[(size_t)b * 64 * SN + (size_t)g * SN + n] = (n < NNODE) ? f2bf(acc) : 0;
}

// ---------------------------------------------------------------------------
// prepack conv2 weights: cw2 [oc][ic][3][3] fp32 -> W2p [tap][oc][ic] bf16
// ---------------------------------------------------------------------------
__global__ __launch_bounds__(256) void k_prepack(const float* __restrict__ w,
                                                 ushort_t* __restrict__ W2p) {
    int idx = blockIdx.x * 256 + threadIdx.x;   // 9*64*64 = 36864
    if (idx >= 36864) return;
    int tap = idx >> 12, rem = idx & 4095;
    int oc = rem >> 6, ic = rem & 63;
    W2p[idx] = f2bf(w[(oc * 64 + ic) * 9 + tap]);
}

// ---------------------------------------------------------------------------
// conv2f: FUSED conv1 -> conv2(MFMA) -> conv3 channel-contraction.
// ---------------------------------------------------------------------------
__global__ __launch_bounds__(256) void k_conv2f(const float* __restrict__ in,
                                                const float* __restrict__ w1,
                                                const float* __restrict__ b1,
                                                const ushort_t* __restrict__ W2p,
                                                const float* __restrict__ b2,
                                                const float* __restrict__ w3c,
                                                float* __restrict__ U) {
    __shared__ ushort_t Xs[340 * 72];           // 48,960 B
    __shared__ float pre[1088];                 // 4,352 B (overlaid)
    const int b = blockIdx.z;
    const float* inb = in + (size_t)b * NPIX;
    float* Uball = U + (size_t)b * 9 * NPIX;
    const int t = threadIdx.x;
    const int lane = t & 63, w = t >> 6;
    const int l15 = lane & 15, q = lane >> 4;
    const int x0 = blockIdx.x * 32, y0 = blockIdx.y * 8;

    float* sI  = pre;                           // [12][36] input halo^2
    float* ws1 = pre + 432;                     // [576] conv1 weights
    float* bs1 = pre + 1008;                    // [64]  conv1 bias

    for (int idx = t; idx < 432; idx += 256) {
        int yy = idx / 36, xx = idx - yy * 36;
        int gy = y0 + yy - 2, gx = x0 + xx - 2;
        sI[idx] = (gy >= 0 && gy < IMG && gx >= 0 && gx < IMG) ? inb[gy * IMG + gx] : 0.f;
    }
    for (int idx = t; idx < 576; idx += 256) ws1[idx] = w1[idx];
    if (t < 64) bs1[t] = b1[t];
    __syncthreads();

    // conv1 -> Xs: 340 halo px x 64 ch (8 ch per (px,s) work item)
    for (int idx = t; idx < 2720; idx += 256) {
        int hp = idx >> 3, s = idx & 7;
        int hy = hp / 34, hx = hp - hy * 34;
        int gy = y0 + hy - 1, gx = x0 + hx - 1;
        unsigned pk[4] = {0u, 0u, 0u, 0u};
        if (gy >= 0 && gy < IMG && gx >= 0 && gx < IMG) {
            float r[9];
#pragma unroll
            for (int dy = 0; dy < 3; ++dy)
#pragma unroll
                for (int dx = 0; dx < 3; ++dx)
                    r[dy * 3 + dx] = sI[(hy + dy) * 36 + hx + dx];
#pragma unroll
            for (int h = 0; h < 4; ++h) {
                int oc0 = s * 8 + h * 2;
                float a0 = bs1[oc0], a1 = bs1[oc0 + 1];
#pragma unroll
                for (int k = 0; k < 9; ++k) {
                    a0 += r[k] * ws1[oc0 * 9 + k];
                    a1 += r[k] * ws1[(oc0 + 1) * 9 + k];
                }
                a0 = fmaxf(a0, 0.f); a1 = fmaxf(a1, 0.f);
                pk[h] = (unsigned)f2bf(a0) | ((unsigned)f2bf(a1) << 16);
            }
        }
        *(uint4*)&Xs[hp * 72 + s * 8] = *(uint4*)pk;
    }
    __syncthreads();                             // Xs ready; pre phase-A reads done

    // phase B: stage conv3 weights into pre (K-loop reads only Xs/W2p)
    for (int idx = t; idx < 576; idx += 256) pre[idx] = w3c[idx];

    const int wn0 = w * 64;
    int pbase[4];
#pragma unroll
    for (int j = 0; j < 4; ++j) {
        int p = wn0 + j * 16 + l15;
        pbase[j] = (p >> 5) * 34 + (p & 31);
    }

    float4v acc[4][4];
#pragma unroll
    for (int i = 0; i < 4; ++i)
#pragma unroll
        for (int j = 0; j < 4; ++j)
#pragma unroll
            for (int r = 0; r < 4; ++r) acc[i][j][r] = 0.f;

    for (int tap = 0; tap < 9; ++tap) {
        int ky = tap / 3, kx = tap - ky * 3;
        const ushort_t* wp = W2p + tap * 4096;
#pragma unroll
        for (int c = 0; c < 2; ++c) {
            short8 af[4], bf[4];
#pragma unroll
            for (int i = 0; i < 4; ++i)
                af[i] = *(const short8*)&wp[(i * 16 + l15) * 64 + c * 32 + q * 8];
#pragma unroll
            for (int j = 0; j < 4; ++j)
                bf[j] = *(const short8*)&Xs[(pbase[j] + ky * 34 + kx) * 72 + c * 32 + q * 8];
#pragma unroll
            for (int i = 0; i < 4; ++i)
#pragma unroll
                for (int j = 0; j < 4; ++j)
                    acc[i][j] = __builtin_amdgcn_mfma_f32_16x16x32_bf16(
                        af[i], bf[j], acc[i][j], 0, 0, 0);
        }
    }
    __syncthreads();                             // w3c visible to all threads

    // epilogue: relu(conv2+b2), contract over oc against w3c -> 9 U planes
    float b2r[16];
#pragma unroll
    for (int i = 0; i < 4; ++i)
#pragma unroll
        for (int r = 0; r < 4; ++r) b2r[i * 4 + r] = b2[i * 16 + q * 4 + r];

#pragma unroll
    for (int j = 0; j < 4; ++j) {
        float u[9];
#pragma unroll
        for (int d = 0; d < 9; ++d) u[d] = 0.f;
#pragma unroll
        for (int i = 0; i < 4; ++i)
#pragma unroll
            for (int r = 0; r < 4; ++r) {
                int oc = i * 16 + q * 4 + r;
                float h = fmaxf(acc[i][j][r] + b2r[i * 4 + r], 0.f);
#pragma unroll
                for (int d = 0; d < 9; ++d) u[d] += h * pre[oc * 9 + d];
            }
#pragma unroll
        for (int d = 0; d < 9; ++d) {
            u[d] += __shfl_xor(u[d], 16, 64);
            u[d] += __shfl_xor(u[d], 32, 64);
        }
        int p = wn0 + j * 16 + l15;
        int y = y0 + (p >> 5), x = x0 + (p & 31);
#pragma unroll
        for (int dd = 0; dd < 3; ++dd) {
            int d = q + dd * 4;                 // q0:{0,4,8} q1:{1,5} q2:{2,6} q3:{3,7}
            if (d < 9)
                Uball[(size_t)d * NPIX + (size_t)y * IMG + x] = u[d];
        }
    }
}

// ---------------------------------------------------------------------------
// combine: out = relu( tmp1 + [bc3 + sum_d U_d(p+off(d))] + gather(g2T+gb4)/cnt )
// ---------------------------------------------------------------------------
__global__ __launch_bounds__(256) void k_combine(const float* __restrict__ in,
                                                 const float* __restrict__ proj,
                                                 const float* __restrict__ lamp,
                                                 const float* __restrict__ U,
                                                 const float* __restrict__ bc,
                                                 const float* __restrict__ g2T,
                                                 const float* __restrict__ gb4,
                                                 float* __restrict__ out) {
    int b = blockIdx.z;
    const float* inb = in + (size_t)b * NPIX;
    const float* prb = proj + (size_t)b * NPIX;
    const float* Ub = U + (size_t)b * 9 * NPIX;
    const float* g2b = g2T + (size_t)b * 64 * SN;
    int tx = threadIdx.x & 15, ty = threadIdx.x >> 4;
    int x = blockIdx.x * 16 + tx, y = blockIdx.y * 16 + ty;

    float acc = bc[0];
#pragma unroll
    for (int dy = 0; dy < 3; ++dy) {
        int yy = y + dy - 1;
#pragma unroll
        for (int dx = 0; dx < 3; ++dx) {
            int xx = x + dx - 1;
            if (yy >= 0 && yy < IMG && xx >= 0 && xx < IMG)
                acc += Ub[(size_t)(dy * 3 + dx) * NPIX + (size_t)yy * IMG + xx];
        }
    }

    float iv = inb[y * IMG + x], pv = prb[y * IMG + x];
    float tmp1 = iv + lamp[0] * (pv - iv);

    int pylo = (y >= 4) ? ((y - 4) >> 2) : 0;
    int pyhi = min(62, y >> 2);
    int pxlo = (x >= 4) ? ((x - 4) >> 2) : 0;
    int pxhi = min(62, x >> 2);
    float sum = 0.f;
    int cnt = 0;
    for (int py = pylo; py <= pyhi; ++py)
        for (int px = pxlo; px <= pxhi; ++px) {
            int pix = (y - 4 * py) * 8 + (x - 4 * px);
            sum += g2b[(size_t)pix * SN + (py * PH + px)] + gb4[pix];
            ++cnt;
        }
    float tmp3 = sum / (float)cnt;

    out[(size_t)b * NPIX + y * IMG + x] = fmaxf(tmp1 + acc + tmp3, 0.f);
}

// ---------------------------------------------------------------------------
extern "C" void kernel_launch(void* const* d_in, const int* in_sizes, int n_in,
                              void* d_out, int out_size, void* d_ws, size_t ws_size,
                              hipStream_t stream) {
    const float* input = (const float*)d_in[0];
    const float* proj  = (const float*)d_in[1];
    const float* adj   = (const float*)d_in[2];
    const float* lam   = (const float*)d_in[3];
    const float* cw1   = (const float*)d_in[4];
    const float* cb1   = (const float*)d_in[5];
    const float* cw2   = (const float*)d_in[6];
    const float* cb2   = (const float*)d_in[7];
    const float* cw3   = (const float*)d_in[8];
    const float* cb3   = (const float*)d_in[9];
    const float* gw3   = (const float*)d_in[10];
    const float* gb3   = (const float*)d_in[11];
    const float* gw4   = (const float*)d_in[12];
    const float* gb4   = (const float*)d_in[13];
    float* out = (float*)d_out;

    // ws layout (bytes), total 178,208,000:
    //   g2T fp32 [4][64][SN]                    @ 0            (4,096,000)
    //   pool @ 4,096,000:
    //     adjb  bf16 [4][N][SN]                 @ +0           (127,008,000)
    //     sup1T bf16 [4][128][SN]               @ +127,008,000 (4,096,000)
    //     g1T   fp32 [4][128][SN]               @ +131,104,000 (8,192,000)
    //     sup2T bf16 [4][64][SN]                @ +139,296,000 (2,048,000)
    //     shared @ +141,344,000                                (32,768,000):
    //       g1P fp32 [4ks][4][128][SN]  (32,768,000)  dead after red128
    //       g2P fp32 [4ks][4][64][SN]   (16,384,000)  alias g1P, dead after red64
    //       U   fp32 [4][9][NPIX]       (9,437,184)   alias g2P (after red64)
    //       W2p bf16 [9][64][64]        (73,728)      @ shared+9,437,184
    char* base = (char*)d_ws;
    float*    g2T   = (float*)base;
    char*     pool  = base + 4096000;
    ushort_t* adjb  = (ushort_t*)pool;
    ushort_t* sup1T = (ushort_t*)(pool + 127008000);
    float*    g1T   = (float*)(pool + 131104000);
    ushort_t* sup2T = (ushort_t*)(pool + 139296000);
    char*     shared = pool + 141344000;
    float*    g1P   = (float*)shared;
    float*    g2P   = (float*)shared;            // alias: g1P dead after red128
    float*    U     = (float*)shared;            // alias: g2P dead after red64
    ushort_t* W2p   = (ushort_t*)(shared + 9437184);

    dim3 blk(256);

    // GCN branch (bf16 MFMA, atomic-free partial accumulation, 64-node tiles)
    k_cvt_adj<<<dim3(NNODE, BATCH), blk, 0, stream>>>(adj, adjb);
    k_sup1<<<dim3(125, 16, BATCH), blk, 0, stream>>>(input, gw3, sup1T);
    k_gemm_mfma<128><<<dim3(63, 4, BATCH), blk, 0, stream>>>(adjb, sup1T, g1P);
    k_red4<<<dim3(2000), blk, 0, stream>>>(g1P, g1T, 512000, 512000);
    k_sup2<<<dim3(125, 8, BATCH), blk, 0, stream>>>(g1T, gb3, gw4, sup2T);
    k_gemm_mfma<64><<<dim3(63, 4, BATCH), blk, 0, stream>>>(adjb, sup2T, g2P);
    k_red4<<<dim3(1000), blk, 0, stream>>>(g2P, g2T, 256000, 256000);

    // CNN branch + combine (prepack/conv2f after red64: W2p/U alias g1P/g2P)
    k_prepack<<<dim3(144), blk, 0, stream>>>(cw2, W2p);
    k_conv2f<<<dim3(8, 32, BATCH), blk, 0, stream>>>(input, cw1, cb1, W2p, cb2, cw3, U);
    k_combine<<<dim3(16, 16, BATCH), blk, 0, stream>>>(
        input, proj, lam, U, cb3, g2T, gb4, out);
}